// Round 19
// baseline (221.601 us; speedup 1.0000x reference)
//
#include <hip/hip_runtime.h>
#include <hip/hip_bf16.h>

// Problem constants
#define N_NODES 50000
#define E_EDGES 800000
#define D_IN    256
#define H_HEADS 4
#define HF      128          // H*F
#define NEG_SLOPE 0.2f
#define SCAN_BLOCKS ((N_NODES + 255) / 256)   // 196
#define PREP_BLOCKS 128                       // 32768 W elems / 256
#define ZERO_BLOCKS SCAN_BLOCKS               // 196
#define GEMM_BLOCKS ((N_NODES + 63) / 64)     // 782

// hist role @512 threads: 313 blocks x 512 x 5 = 801,280 >= E (guarded)
#define HIST_BLOCKS5 313
#define HIST_STRIDE5 (HIST_BLOCKS5 * 512)     // 160,256

// fill v3: XCD-exclusive dst windows
#define FILL_WINDOWS 8
#define FILL_WIN_NODES (N_NODES / FILL_WINDOWS)     // 6250
#define FILL_EDGES_PER_SLICE 2048
#define FILL_SLICES ((E_EDGES + FILL_EDGES_PER_SLICE - 1) / FILL_EDGES_PER_SLICE) // 391

typedef __attribute__((ext_vector_type(8))) short bf16x8;   // 8 bf16 = 4 VGPRs
typedef __attribute__((ext_vector_type(4))) float f32x4;

__device__ __forceinline__ float bf_lo(unsigned u) { return __uint_as_float(u << 16); }
__device__ __forceinline__ float bf_hi(unsigned u) { return __uint_as_float(u & 0xFFFF0000u); }

// ---------------------------------------------------------------------------
// K_a: fat = [zero cnt: 196 blocks] + [prepW: 128 blocks]. Both trivial.
// ---------------------------------------------------------------------------
__global__ __launch_bounds__(256) void k_zero_prep(unsigned* __restrict__ cnt,
                                                   const float* __restrict__ W,
                                                   __hip_bfloat16* __restrict__ Wt) {
    const int b = blockIdx.x;
    if (b < ZERO_BLOCKS) {
        const int g = b * 256 + threadIdx.x;
        if (g < N_NODES) cnt[g] = 0u;
    } else {
        const int g = (b - ZERO_BLOCKS) * 256 + threadIdx.x;  // over 32768
        const int n = g >> 8;
        const int k = g & 255;
        Wt[n * D_IN + k] = __float2bfloat16(W[k * HF + n]);
    }
}

// ---------------------------------------------------------------------------
// K_b v3 (R16): 512-thread blocks (8 waves), same 64x128 tile, fused hist.
// R16 counters: occupancy 31% = GRID-limited (782 blocks x 4 waves ~ 12
// waves/CU; LDS allows 5 blocks/CU, VGPR=56 allows 8 waves/SIMD). The
// 4-iteration stage->barrier->MFMA chain has too few resident waves to
// hide. 8 waves/block: wr=wave&3 owns a 16-row group, wc=wave>>2 owns a
// 64-col half; acc 8->4 f32x4 (VGPR stays <=64). h still read ONCE per
// tile (51MB total). Per-CU waves 12 -> 24. Hist re-tiled for 512.
// History: R4 LDS structure 44-48us x3 best; LDS-free 67us (R12);
// split-out hist +13us (R14). Fusion + LDS staging stand.
// ---------------------------------------------------------------------------
__global__ __launch_bounds__(512) void k_gemm_hist(const float* __restrict__ h,
                                                   const __hip_bfloat16* __restrict__ Wt,
                                                   const float* __restrict__ lw,
                                                   const float* __restrict__ lb,
                                                   const float* __restrict__ rw,
                                                   const float* __restrict__ rb,
                                                   __hip_bfloat16* __restrict__ hW,
                                                   float* __restrict__ el,
                                                   float* __restrict__ er,
                                                   const int* __restrict__ dst,
                                                   unsigned* __restrict__ cnt) {
    __shared__ __hip_bfloat16 As[64][72];
    __shared__ __hip_bfloat16 Bs[128][72];

    if (blockIdx.x >= GEMM_BLOCKS) {
        // ---- hist role: 5 edges per thread over 512-thread blocks ----
        const int g0 = (blockIdx.x - GEMM_BLOCKS) * 512 + threadIdx.x;
        int d[5]; bool ok[5];
        #pragma unroll
        for (int i = 0; i < 5; ++i) {
            const int g = g0 + i * HIST_STRIDE5;
            ok[i] = (g < E_EDGES);
            d[i] = ok[i] ? dst[g] : 0;
        }
        #pragma unroll
        for (int i = 0; i < 5; ++i)
            if (ok[i]) atomicAdd(&cnt[d[i]], 1u);
        return;
    }

    // ---- gemm role: 8 waves, wr = row-group, wc = col-half ----
    const int t    = threadIdx.x;
    const int r0   = blockIdx.x * 64;
    const int wave = t >> 6;
    const int lane = t & 63;
    const int l16  = lane & 15;
    const int quad = lane >> 4;
    const int wr   = wave & 3;       // 16-row group
    const int wc   = wave >> 2;      // 64-col half (0/1)

    f32x4 acc[4] = {};

    for (int k0 = 0; k0 < D_IN; k0 += 64) {
        {   // stage A: 64 rows x 64 k by 512 threads (8 floats each)
            const int row  = t >> 3;
            const int koff = (t & 7) * 8;
            const int n    = r0 + row;
            float v[8];
            if (n < N_NODES) {
                const float* p = h + (size_t)n * D_IN + k0 + koff;
                *(float4*)&v[0] = ((const float4*)p)[0];
                *(float4*)&v[4] = ((const float4*)p)[1];
            } else {
                #pragma unroll
                for (int i = 0; i < 8; ++i) v[i] = 0.f;
            }
            __hip_bfloat16 b[8];
            #pragma unroll
            for (int i = 0; i < 8; ++i) b[i] = __float2bfloat16(v[i]);
            *(uint4*)&As[row][koff] = ((uint4*)b)[0];
        }
        {   // stage B: 128 rows x 64 k by 512 threads (16 bf16 each)
            const int n    = t >> 2;
            const int koff = (t & 3) * 16;
            const uint4* p = (const uint4*)(Wt + n * D_IN + k0 + koff);
            uint4 b0 = p[0], b1 = p[1];
            uint4* q = (uint4*)&Bs[n][koff];
            q[0] = b0; q[1] = b1;
        }
        __syncthreads();

        #pragma unroll
        for (int ks = 0; ks < 2; ++ks) {
            const bf16x8 af = *(const bf16x8*)&As[wr * 16 + l16][ks * 32 + quad * 8];
            #pragma unroll
            for (int nt = 0; nt < 4; ++nt) {
                const bf16x8 bfg =
                    *(const bf16x8*)&Bs[wc * 64 + nt * 16 + l16][ks * 32 + quad * 8];
                acc[nt] = __builtin_amdgcn_mfma_f32_16x16x32_bf16(af, bfg, acc[nt], 0, 0, 0);
            }
        }
        __syncthreads();
    }

    const int mbase = r0 + wr * 16 + quad * 4;
    #pragma unroll
    for (int nt = 0; nt < 4; ++nt) {
        #pragma unroll
        for (int r = 0; r < 4; ++r) {
            const int m = mbase + r;
            if (m < N_NODES)
                hW[(size_t)m * HF + wc * 64 + nt * 16 + l16] = __float2bfloat16(acc[nt][r]);
        }
    }

    // el/er: this wave covers heads hh = wc*2 + hh2 (hh2 in 0..1).
    // acc[2*hh2] covers features l16, acc[2*hh2+1] covers l16+16.
    const float lwv0 = lw[l16], lwv1 = lw[l16 + 16];
    const float rwv0 = rw[l16], rwv1 = rw[l16 + 16];
    const float lb0 = lb[0], rb0 = rb[0];
    #pragma unroll
    for (int r = 0; r < 4; ++r) {
        const int m = mbase + r;
        float el2[2], er2[2];
        #pragma unroll
        for (int hh2 = 0; hh2 < 2; ++hh2) {
            float pl = acc[2 * hh2][r] * lwv0 + acc[2 * hh2 + 1][r] * lwv1;
            float pr = acc[2 * hh2][r] * rwv0 + acc[2 * hh2 + 1][r] * rwv1;
            #pragma unroll
            for (int o = 1; o < 16; o <<= 1) {
                pl += __shfl_xor(pl, o);
                pr += __shfl_xor(pr, o);
            }
            el2[hh2] = pl + lb0;
            er2[hh2] = pr + rb0;
        }
        if (l16 == 0 && m < N_NODES) {
            *(float2*)&el[m * H_HEADS + wc * 2] = make_float2(el2[0], el2[1]);
            *(float2*)&er[m * H_HEADS + wc * 2] = make_float2(er2[0], er2[1]);
        }
    }
}

// ---------------------------------------------------------------------------
// k_bsum (R14, validated R16): block b tree-reduces its cnt chunk -> bsum[b].
// Plain loads + LDS reduce, NO atomics (convoy-free).
// ---------------------------------------------------------------------------
__global__ __launch_bounds__(256) void k_bsum(const unsigned* __restrict__ cnt,
                                              unsigned* __restrict__ bsum) {
    __shared__ unsigned s[256];
    const int t = threadIdx.x;
    const int g = blockIdx.x * 256 + t;
    s[t] = (g < N_NODES) ? cnt[g] : 0u;
    __syncthreads();
    #pragma unroll
    for (int o = 128; o > 0; o >>= 1) {
        if (t < o) s[t] += s[t + o];
        __syncthreads();
    }
    if (t == 0) bsum[blockIdx.x] = s[0];
}

// ---------------------------------------------------------------------------
// k_scan v3 (R14, validated R16): prefix phase sums bsum[0..b), own-chunk
// 256-elem inclusive scan unchanged.
// ---------------------------------------------------------------------------
__global__ __launch_bounds__(256) void k_scan(const unsigned* __restrict__ cnt,
                                              unsigned* __restrict__ off,
                                              const unsigned* __restrict__ bsum) {
    __shared__ unsigned s[256];
    const int t = threadIdx.x;
    const int b = blockIdx.x;
    const int base = b * 256;

    s[t] = (t < b) ? bsum[t] : 0u;
    __syncthreads();
    #pragma unroll
    for (int o = 128; o > 0; o >>= 1) {
        if (t < o) s[t] += s[t + o];
        __syncthreads();
    }
    const unsigned pre = s[0];
    __syncthreads();

    const int g = base + t;
    const unsigned x = (g < N_NODES) ? cnt[g] : 0u;
    s[t] = x;
    __syncthreads();
    unsigned inc = x;
    #pragma unroll
    for (int o = 1; o < 256; o <<= 1) {
        const unsigned v = (t >= o) ? s[t - o] : 0u;
        __syncthreads();
        inc += v;
        s[t] = inc;
        __syncthreads();
    }
    if (g < N_NODES) off[g] = pre + inc - x;   // exclusive
}

// ---------------------------------------------------------------------------
// K_fill v3: XCD-exclusive dst-window scatter (part of the 220.1 best).
// ---------------------------------------------------------------------------
__global__ __launch_bounds__(256) void k_fill(const int* __restrict__ src,
                                              const int* __restrict__ dst,
                                              unsigned* __restrict__ off,
                                              unsigned* __restrict__ perm) {
    const int win   = blockIdx.x & 7;
    const int slice = blockIdx.x >> 3;
    const int base  = slice * FILL_EDGES_PER_SLICE + threadIdx.x;
    const int lo    = win * FILL_WIN_NODES;
    #pragma unroll
    for (int i = 0; i < 8; ++i) {
        const int g = base + i * 256;
        if (g < E_EDGES) {
            const int d = dst[g];
            if ((unsigned)(d - lo) < (unsigned)FILL_WIN_NODES) {
                const unsigned p = atomicAdd(&off[d], 1u);
                perm[p] = (unsigned)src[g];
            }
        }
    }
}

// ---------------------------------------------------------------------------
// K5: per-node softmax + weighted gather-sum (part of the 220.1 best).
// Wave-per-node, 8 edges/step, 4-edge middle + 2-edge tail.
// ---------------------------------------------------------------------------
__global__ __launch_bounds__(256) void k_aggregate(const __hip_bfloat16* __restrict__ hW,
                                                   const float* __restrict__ el,
                                                   const float* __restrict__ er,
                                                   const unsigned* __restrict__ off_end,
                                                   const unsigned* __restrict__ perm,
                                                   const float* __restrict__ bias,
                                                   float* __restrict__ out) {
    const int wave = threadIdx.x >> 6;
    const int lane = threadIdx.x & 63;
    const int half = lane >> 5;                    // 0: even edge, 1: odd edge
    const int l    = lane & 31;                    // features 4*l .. 4*l+3
    const int hh   = l >> 3;
    const int n    = blockIdx.x * 4 + wave;        // 12500*4 = 50000 exact
    const unsigned beg = (n == 0) ? 0u : off_end[n - 1];
    const unsigned end = off_end[n];
    const float eld = el[(unsigned)n * H_HEADS + hh];
    const uint2* hW2 = (const uint2*)hW;           // 8B granules: row = 32

    float a0 = 0.f, a1 = 0.f, a2 = 0.f, a3 = 0.f, denom = 0.f;
    unsigned j = beg;
    for (; j + 8 <= end; j += 8) {                 // 8 edges per step
        const unsigned s0 = perm[j + half];
        const unsigned s1 = perm[j + 2 + half];
        const unsigned s2 = perm[j + 4 + half];
        const unsigned s3 = perm[j + 6 + half];
        const float er0 = er[s0 * H_HEADS + hh];
        const float er1 = er[s1 * H_HEADS + hh];
        const float er2 = er[s2 * H_HEADS + hh];
        const float er3 = er[s3 * H_HEADS + hh];
        const uint2 g0 = hW2[s0 * 32u + l];
        const uint2 g1 = hW2[s1 * 32u + l];
        const uint2 g2 = hW2[s2 * 32u + l];
        const uint2 g3 = hW2[s3 * 32u + l];
        float v0 = er0 + eld; v0 = (v0 >= 0.f) ? v0 : NEG_SLOPE * v0;
        float v1 = er1 + eld; v1 = (v1 >= 0.f) ? v1 : NEG_SLOPE * v1;
        float v2 = er2 + eld; v2 = (v2 >= 0.f) ? v2 : NEG_SLOPE * v2;
        float v3 = er3 + eld; v3 = (v3 >= 0.f) ? v3 : NEG_SLOPE * v3;
        const float p0 = __expf(v0);
        const float p1 = __expf(v1);
        const float p2 = __expf(v2);
        const float p3 = __expf(v3);
        denom += (p0 + p1) + (p2 + p3);
        a0 += p0 * bf_lo(g0.x) + p1 * bf_lo(g1.x) + p2 * bf_lo(g2.x) + p3 * bf_lo(g3.x);
        a1 += p0 * bf_hi(g0.x) + p1 * bf_hi(g1.x) + p2 * bf_hi(g2.x) + p3 * bf_hi(g3.x);
        a2 += p0 * bf_lo(g0.y) + p1 * bf_lo(g1.y) + p2 * bf_lo(g2.y) + p3 * bf_lo(g3.y);
        a3 += p0 * bf_hi(g0.y) + p1 * bf_hi(g1.y) + p2 * bf_hi(g2.y) + p3 * bf_hi(g3.y);
    }
    if (j + 4 <= end) {                            // 4-edge middle
        const unsigned s0 = perm[j + half];
        const unsigned s1 = perm[j + 2 + half];
        const float er0 = er[s0 * H_HEADS + hh];
        const float er1 = er[s1 * H_HEADS + hh];
        const uint2 g0 = hW2[s0 * 32u + l];
        const uint2 g1 = hW2[s1 * 32u + l];
        float v0 = er0 + eld; v0 = (v0 >= 0.f) ? v0 : NEG_SLOPE * v0;
        float v1 = er1 + eld; v1 = (v1 >= 0.f) ? v1 : NEG_SLOPE * v1;
        const float p0 = __expf(v0);
        const float p1 = __expf(v1);
        denom += p0 + p1;
        a0 += p0 * bf_lo(g0.x) + p1 * bf_lo(g1.x);
        a1 += p0 * bf_hi(g0.x) + p1 * bf_hi(g1.x);
        a2 += p0 * bf_lo(g0.y) + p1 * bf_lo(g1.y);
        a3 += p0 * bf_hi(g0.y) + p1 * bf_hi(g1.y);
        j += 4;
    }
    for (; j < end; j += 2) {                      // tail: 1..3 edges
        const unsigned i = j + half;
        const bool ok = (i < end);
        const unsigned s = ok ? perm[i] : 0u;
        const float erv = er[s * H_HEADS + hh];
        const uint2 g = hW2[s * 32u + l];
        float v = erv + eld; v = (v >= 0.f) ? v : NEG_SLOPE * v;
        const float p = ok ? __expf(v) : 0.f;
        denom += p;
        a0 += p * bf_lo(g.x);
        a1 += p * bf_hi(g.x);
        a2 += p * bf_lo(g.y);
        a3 += p * bf_hi(g.y);
    }
    // combine even/odd halves
    denom += __shfl_xor(denom, 32);
    a0 += __shfl_xor(a0, 32);
    a1 += __shfl_xor(a1, 32);
    a2 += __shfl_xor(a2, 32);
    a3 += __shfl_xor(a3, 32);
    if (half == 0) {
        const float inv = (end > beg) ? 1.f / denom : 0.f;
        const float4 bv = *(const float4*)&bias[l * 4];
        float4 o = make_float4(a0 * inv + bv.x, a1 * inv + bv.y,
                               a2 * inv + bv.z, a3 * inv + bv.w);
        *(float4*)&out[(unsigned)n * HF + l * 4] = o;
    }
}

// ---------------------------------------------------------------------------
// launch — ws (float units): el 0 / er 200k / cnt 400k / off 450k /
// perm 500k / Wt 1300k / bsum 1316500 (196 u32) / hW 1320k..4520k
// => 18.1 MB (ws-safe).
// 6 dispatches: [zero|prepW] -> [gemm|hist]@512 -> bsum -> scan -> fill -> agg.
// ---------------------------------------------------------------------------
extern "C" void kernel_launch(void* const* d_in, const int* in_sizes, int n_in,
                              void* d_out, int out_size, void* d_ws, size_t ws_size,
                              hipStream_t stream) {
    const float* h    = (const float*)d_in[0];
    const float* W    = (const float*)d_in[1];
    const float* lw   = (const float*)d_in[2];
    const float* lb   = (const float*)d_in[3];
    const float* rw   = (const float*)d_in[4];
    const float* rb   = (const float*)d_in[5];
    const float* bias = (const float*)d_in[6];
    const int*   src  = (const int*)d_in[7];
    const int*   dst  = (const int*)d_in[8];
    float* out = (float*)d_out;

    float*    ws   = (float*)d_ws;
    float*    el   = ws;                           // 200,000 f
    float*    er   = ws + 200000;                  // 200,000 f
    unsigned* cnt  = (unsigned*)(ws + 400000);     //  50,000 u32
    unsigned* off  = (unsigned*)(ws + 450000);     //  50,000 u32
    unsigned* perm = (unsigned*)(ws + 500000);     // 800,000 u32
    __hip_bfloat16* Wt = (__hip_bfloat16*)(ws + 1300000);  // 32,768 bf16
    unsigned* bsum = (unsigned*)(ws + 1316500);    // 196 u32 (gap before hW)
    __hip_bfloat16* hW = (__hip_bfloat16*)(ws + 1320000);  // 6.4M bf16

    k_zero_prep<<<ZERO_BLOCKS + PREP_BLOCKS, 256, 0, stream>>>(cnt, W, Wt);
    k_gemm_hist<<<GEMM_BLOCKS + HIST_BLOCKS5, 512, 0, stream>>>(
        h, Wt, lw, lb, rw, rb, hW, el, er, dst, cnt);
    k_bsum<<<SCAN_BLOCKS, 256, 0, stream>>>(cnt, bsum);
    k_scan<<<SCAN_BLOCKS, 256, 0, stream>>>(cnt, off, bsum);
    k_fill<<<FILL_SLICES * FILL_WINDOWS, 256, 0, stream>>>(src, dst, off, perm);
    k_aggregate<<<N_NODES / 4, 256, 0, stream>>>(hW, el, er, off, perm, bias, out);
}

// Round 21
// 219.275 us; speedup vs baseline: 1.0106x; 1.0106x over previous
//
#include <hip/hip_runtime.h>
#include <hip/hip_bf16.h>

// Problem constants
#define N_NODES 50000
#define E_EDGES 800000
#define D_IN    256
#define H_HEADS 4
#define HF      128          // H*F
#define NEG_SLOPE 0.2f
#define SCAN_BLOCKS ((N_NODES + 255) / 256)   // 196
#define PREP_BLOCKS 128                       // 32768 W elems / 256
#define ZERO_BLOCKS SCAN_BLOCKS               // 196
#define GEMM_BLOCKS ((N_NODES + 63) / 64)     // 782

// hist role: fat blocks, 5 edges/thread (625*256*5 = 800000 exact)
#define HIST_FAT_BLOCKS 625
#define HIST_STRIDE (HIST_FAT_BLOCKS * 256)   // 160000

// fill v3: XCD-exclusive dst windows
#define FILL_WINDOWS 8
#define FILL_WIN_NODES (N_NODES / FILL_WINDOWS)     // 6250
#define FILL_EDGES_PER_SLICE 2048
#define FILL_SLICES ((E_EDGES + FILL_EDGES_PER_SLICE - 1) / FILL_EDGES_PER_SLICE) // 391

typedef __attribute__((ext_vector_type(8))) short bf16x8;   // 8 bf16 = 4 VGPRs
typedef __attribute__((ext_vector_type(4))) float f32x4;

__device__ __forceinline__ float bf_lo(unsigned u) { return __uint_as_float(u << 16); }
__device__ __forceinline__ float bf_hi(unsigned u) { return __uint_as_float(u & 0xFFFF0000u); }

// ---------------------------------------------------------------------------
// K_a: fat = [zero cnt: 196 blocks] + [prepW: 128 blocks]. Both trivial.
// ---------------------------------------------------------------------------
__global__ __launch_bounds__(256) void k_zero_prep(unsigned* __restrict__ cnt,
                                                   const float* __restrict__ W,
                                                   __hip_bfloat16* __restrict__ Wt) {
    const int b = blockIdx.x;
    if (b < ZERO_BLOCKS) {
        const int g = b * 256 + threadIdx.x;
        if (g < N_NODES) cnt[g] = 0u;
    } else {
        const int g = (b - ZERO_BLOCKS) * 256 + threadIdx.x;  // over 32768
        const int n = g >> 8;
        const int k = g & 255;
        Wt[n * D_IN + k] = __float2bfloat16(W[k * HF + n]);
    }
}

// ---------------------------------------------------------------------------
// K_b (256-thread, R16-measured-best config, 220.1us total).
// R19 verdict: 512-thread variant doubled occupancy (31->58%) with ZERO
// duration change (48.5us both) -> occupancy was NOT the limiter; the
// barrier-per-K-step structure is a latency/issue floor that more TLP
// doesn't touch (matches guide m99-m141: source-level pipelining is
// compiler-bound). Gemm declared at practical floor ~48us after 3 failed
// attack axes (LDS-free +19us, fat-hist 0, occupancy 0).
// ---------------------------------------------------------------------------
__global__ __launch_bounds__(256) void k_gemm_hist(const float* __restrict__ h,
                                                   const __hip_bfloat16* __restrict__ Wt,
                                                   const float* __restrict__ lw,
                                                   const float* __restrict__ lb,
                                                   const float* __restrict__ rw,
                                                   const float* __restrict__ rb,
                                                   __hip_bfloat16* __restrict__ hW,
                                                   float* __restrict__ el,
                                                   float* __restrict__ er,
                                                   const int* __restrict__ dst,
                                                   unsigned* __restrict__ cnt) {
    __shared__ __hip_bfloat16 As[64][72];
    __shared__ __hip_bfloat16 Bs[128][72];

    if (blockIdx.x >= GEMM_BLOCKS) {
        // ---- hist role: 5 edges per thread, stride HIST_STRIDE ----
        const int g0 = (blockIdx.x - GEMM_BLOCKS) * 256 + threadIdx.x;
        int d[5];
        #pragma unroll
        for (int i = 0; i < 5; ++i) d[i] = dst[g0 + i * HIST_STRIDE];
        #pragma unroll
        for (int i = 0; i < 5; ++i) atomicAdd(&cnt[d[i]], 1u);
        return;
    }

    // ---- gemm role ----
    const int t    = threadIdx.x;
    const int r0   = blockIdx.x * 64;
    const int wave = t >> 6;
    const int lane = t & 63;
    const int l16  = lane & 15;
    const int quad = lane >> 4;

    f32x4 acc[8] = {};

    for (int k0 = 0; k0 < D_IN; k0 += 64) {
        {   // stage A: 64 rows x 64 k, fp32 -> bf16
            const int row  = t >> 2;
            const int koff = (t & 3) * 16;
            const int n    = r0 + row;
            float v[16];
            if (n < N_NODES) {
                const float* p = h + (size_t)n * D_IN + k0 + koff;
                *(float4*)&v[0]  = ((const float4*)p)[0];
                *(float4*)&v[4]  = ((const float4*)p)[1];
                *(float4*)&v[8]  = ((const float4*)p)[2];
                *(float4*)&v[12] = ((const float4*)p)[3];
            } else {
                #pragma unroll
                for (int i = 0; i < 16; ++i) v[i] = 0.f;
            }
            __hip_bfloat16 b[16];
            #pragma unroll
            for (int i = 0; i < 16; ++i) b[i] = __float2bfloat16(v[i]);
            *(uint4*)&As[row][koff]     = ((uint4*)b)[0];
            *(uint4*)&As[row][koff + 8] = ((uint4*)b)[1];
        }
        {   // stage B: 128 n-rows x 64 k from Wt (bf16)
            const int n    = t >> 1;
            const int koff = (t & 1) * 32;
            const uint4* p = (const uint4*)(Wt + n * D_IN + k0 + koff);
            uint4 b0 = p[0], b1 = p[1], b2 = p[2], b3 = p[3];
            uint4* q = (uint4*)&Bs[n][koff];
            q[0] = b0; q[1] = b1; q[2] = b2; q[3] = b3;
        }
        __syncthreads();

        #pragma unroll
        for (int ks = 0; ks < 2; ++ks) {
            const bf16x8 af = *(const bf16x8*)&As[wave * 16 + l16][ks * 32 + quad * 8];
            #pragma unroll
            for (int nt = 0; nt < 8; ++nt) {
                const bf16x8 bfg = *(const bf16x8*)&Bs[nt * 16 + l16][ks * 32 + quad * 8];
                acc[nt] = __builtin_amdgcn_mfma_f32_16x16x32_bf16(af, bfg, acc[nt], 0, 0, 0);
            }
        }
        __syncthreads();
    }

    const int mbase = r0 + wave * 16 + quad * 4;
    #pragma unroll
    for (int nt = 0; nt < 8; ++nt) {
        #pragma unroll
        for (int r = 0; r < 4; ++r) {
            const int m = mbase + r;
            if (m < N_NODES)
                hW[(size_t)m * HF + nt * 16 + l16] = __float2bfloat16(acc[nt][r]);
        }
    }

    const float lwv0 = lw[l16], lwv1 = lw[l16 + 16];
    const float rwv0 = rw[l16], rwv1 = rw[l16 + 16];
    const float lb0 = lb[0], rb0 = rb[0];
    #pragma unroll
    for (int r = 0; r < 4; ++r) {
        const int m = mbase + r;
        float el4[4], er4[4];
        #pragma unroll
        for (int hh = 0; hh < 4; ++hh) {
            float pl = acc[2 * hh][r] * lwv0 + acc[2 * hh + 1][r] * lwv1;
            float pr = acc[2 * hh][r] * rwv0 + acc[2 * hh + 1][r] * rwv1;
            #pragma unroll
            for (int o = 1; o < 16; o <<= 1) {
                pl += __shfl_xor(pl, o);
                pr += __shfl_xor(pr, o);
            }
            el4[hh] = pl + lb0;
            er4[hh] = pr + rb0;
        }
        if (l16 == 0 && m < N_NODES) {
            *(float4*)&el[m * H_HEADS] = make_float4(el4[0], el4[1], el4[2], el4[3]);
            *(float4*)&er[m * H_HEADS] = make_float4(er4[0], er4[1], er4[2], er4[3]);
        }
    }
}

// ---------------------------------------------------------------------------
// k_bsum (validated R16): block b tree-reduces its cnt chunk -> bsum[b].
// ---------------------------------------------------------------------------
__global__ __launch_bounds__(256) void k_bsum(const unsigned* __restrict__ cnt,
                                              unsigned* __restrict__ bsum) {
    __shared__ unsigned s[256];
    const int t = threadIdx.x;
    const int g = blockIdx.x * 256 + t;
    s[t] = (g < N_NODES) ? cnt[g] : 0u;
    __syncthreads();
    #pragma unroll
    for (int o = 128; o > 0; o >>= 1) {
        if (t < o) s[t] += s[t + o];
        __syncthreads();
    }
    if (t == 0) bsum[blockIdx.x] = s[0];
}

// ---------------------------------------------------------------------------
// k_scan v3 (validated R16): prefix phase sums bsum[0..b).
// ---------------------------------------------------------------------------
__global__ __launch_bounds__(256) void k_scan(const unsigned* __restrict__ cnt,
                                              unsigned* __restrict__ off,
                                              const unsigned* __restrict__ bsum) {
    __shared__ unsigned s[256];
    const int t = threadIdx.x;
    const int b = blockIdx.x;
    const int base = b * 256;

    s[t] = (t < b) ? bsum[t] : 0u;
    __syncthreads();
    #pragma unroll
    for (int o = 128; o > 0; o >>= 1) {
        if (t < o) s[t] += s[t + o];
        __syncthreads();
    }
    const unsigned pre = s[0];
    __syncthreads();

    const int g = base + t;
    const unsigned x = (g < N_NODES) ? cnt[g] : 0u;
    s[t] = x;
    __syncthreads();
    unsigned inc = x;
    #pragma unroll
    for (int o = 1; o < 256; o <<= 1) {
        const unsigned v = (t >= o) ? s[t - o] : 0u;
        __syncthreads();
        inc += v;
        s[t] = inc;
        __syncthreads();
    }
    if (g < N_NODES) off[g] = pre + inc - x;   // exclusive
}

// ---------------------------------------------------------------------------
// K_fill v3: XCD-exclusive dst-window scatter (part of the 220.1 best).
// ---------------------------------------------------------------------------
__global__ __launch_bounds__(256) void k_fill(const int* __restrict__ src,
                                              const int* __restrict__ dst,
                                              unsigned* __restrict__ off,
                                              unsigned* __restrict__ perm) {
    const int win   = blockIdx.x & 7;
    const int slice = blockIdx.x >> 3;
    const int base  = slice * FILL_EDGES_PER_SLICE + threadIdx.x;
    const int lo    = win * FILL_WIN_NODES;
    #pragma unroll
    for (int i = 0; i < 8; ++i) {
        const int g = base + i * 256;
        if (g < E_EDGES) {
            const int d = dst[g];
            if ((unsigned)(d - lo) < (unsigned)FILL_WIN_NODES) {
                const unsigned p = atomicAdd(&off[d], 1u);
                perm[p] = (unsigned)src[g];
            }
        }
    }
}

// ---------------------------------------------------------------------------
// K5 v3 (R19): main loop widened 8 -> 16 edges/step (8 independent
// perm->er/hW chains per thread). Theory: avg degree 16 gave only ~2 steps
// of the 8-edge loop -> MLP-starved dependent gather; one 16-edge step
// covers a full average node with 8 chains in flight. 8/4/2-edge blocks
// handle remainders. Diagnostic: total flat => agg is BW/latency-floor'd.
// ---------------------------------------------------------------------------
__global__ __launch_bounds__(256) void k_aggregate(const __hip_bfloat16* __restrict__ hW,
                                                   const float* __restrict__ el,
                                                   const float* __restrict__ er,
                                                   const unsigned* __restrict__ off_end,
                                                   const unsigned* __restrict__ perm,
                                                   const float* __restrict__ bias,
                                                   float* __restrict__ out) {
    const int wave = threadIdx.x >> 6;
    const int lane = threadIdx.x & 63;
    const int half = lane >> 5;                    // 0: even edge, 1: odd edge
    const int l    = lane & 31;                    // features 4*l .. 4*l+3
    const int hh   = l >> 3;
    const int n    = blockIdx.x * 4 + wave;        // 12500*4 = 50000 exact
    const unsigned beg = (n == 0) ? 0u : off_end[n - 1];
    const unsigned end = off_end[n];
    const float eld = el[(unsigned)n * H_HEADS + hh];
    const uint2* hW2 = (const uint2*)hW;           // 8B granules: row = 32

    float a0 = 0.f, a1 = 0.f, a2 = 0.f, a3 = 0.f, denom = 0.f;
    unsigned j = beg;
    for (; j + 16 <= end; j += 16) {               // 16 edges per step, 8 chains
        unsigned ss[8];
        #pragma unroll
        for (int k = 0; k < 8; ++k) ss[k] = perm[j + 2 * k + half];
        float erv[8];
        #pragma unroll
        for (int k = 0; k < 8; ++k) erv[k] = er[ss[k] * H_HEADS + hh];
        uint2 gg[8];
        #pragma unroll
        for (int k = 0; k < 8; ++k) gg[k] = hW2[ss[k] * 32u + l];
        #pragma unroll
        for (int k = 0; k < 8; ++k) {
            float v = erv[k] + eld; v = (v >= 0.f) ? v : NEG_SLOPE * v;
            const float p = __expf(v);
            denom += p;
            a0 += p * bf_lo(gg[k].x);
            a1 += p * bf_hi(gg[k].x);
            a2 += p * bf_lo(gg[k].y);
            a3 += p * bf_hi(gg[k].y);
        }
    }
    if (j + 8 <= end) {                            // 8-edge block
        const unsigned s0 = perm[j + half];
        const unsigned s1 = perm[j + 2 + half];
        const unsigned s2 = perm[j + 4 + half];
        const unsigned s3 = perm[j + 6 + half];
        const float er0 = er[s0 * H_HEADS + hh];
        const float er1 = er[s1 * H_HEADS + hh];
        const float er2 = er[s2 * H_HEADS + hh];
        const float er3 = er[s3 * H_HEADS + hh];
        const uint2 g0 = hW2[s0 * 32u + l];
        const uint2 g1 = hW2[s1 * 32u + l];
        const uint2 g2 = hW2[s2 * 32u + l];
        const uint2 g3 = hW2[s3 * 32u + l];
        float v0 = er0 + eld; v0 = (v0 >= 0.f) ? v0 : NEG_SLOPE * v0;
        float v1 = er1 + eld; v1 = (v1 >= 0.f) ? v1 : NEG_SLOPE * v1;
        float v2 = er2 + eld; v2 = (v2 >= 0.f) ? v2 : NEG_SLOPE * v2;
        float v3 = er3 + eld; v3 = (v3 >= 0.f) ? v3 : NEG_SLOPE * v3;
        const float p0 = __expf(v0);
        const float p1 = __expf(v1);
        const float p2 = __expf(v2);
        const float p3 = __expf(v3);
        denom += (p0 + p1) + (p2 + p3);
        a0 += p0 * bf_lo(g0.x) + p1 * bf_lo(g1.x) + p2 * bf_lo(g2.x) + p3 * bf_lo(g3.x);
        a1 += p0 * bf_hi(g0.x) + p1 * bf_hi(g1.x) + p2 * bf_hi(g2.x) + p3 * bf_hi(g3.x);
        a2 += p0 * bf_lo(g0.y) + p1 * bf_lo(g1.y) + p2 * bf_lo(g2.y) + p3 * bf_lo(g3.y);
        a3 += p0 * bf_hi(g0.y) + p1 * bf_hi(g1.y) + p2 * bf_hi(g2.y) + p3 * bf_hi(g3.y);
        j += 8;
    }
    if (j + 4 <= end) {                            // 4-edge block
        const unsigned s0 = perm[j + half];
        const unsigned s1 = perm[j + 2 + half];
        const float er0 = er[s0 * H_HEADS + hh];
        const float er1 = er[s1 * H_HEADS + hh];
        const uint2 g0 = hW2[s0 * 32u + l];
        const uint2 g1 = hW2[s1 * 32u + l];
        float v0 = er0 + eld; v0 = (v0 >= 0.f) ? v0 : NEG_SLOPE * v0;
        float v1 = er1 + eld; v1 = (v1 >= 0.f) ? v1 : NEG_SLOPE * v1;
        const float p0 = __expf(v0);
        const float p1 = __expf(v1);
        denom += p0 + p1;
        a0 += p0 * bf_lo(g0.x) + p1 * bf_lo(g1.x);
        a1 += p0 * bf_hi(g0.x) + p1 * bf_hi(g1.x);
        a2 += p0 * bf_lo(g0.y) + p1 * bf_lo(g1.y);
        a3 += p0 * bf_hi(g0.y) + p1 * bf_hi(g1.y);
        j += 4;
    }
    for (; j < end; j += 2) {                      // tail: 1..3 edges
        const unsigned i = j + half;
        const bool ok = (i < end);
        const unsigned s = ok ? perm[i] : 0u;
        const float erv = er[s * H_HEADS + hh];
        const uint2 g = hW2[s * 32u + l];
        float v = erv + eld; v = (v >= 0.f) ? v : NEG_SLOPE * v;
        const float p = ok ? __expf(v) : 0.f;
        denom += p;
        a0 += p * bf_lo(g.x);
        a1 += p * bf_hi(g.x);
        a2 += p * bf_lo(g.y);
        a3 += p * bf_hi(g.y);
    }
    // combine even/odd halves
    denom += __shfl_xor(denom, 32);
    a0 += __shfl_xor(a0, 32);
    a1 += __shfl_xor(a1, 32);
    a2 += __shfl_xor(a2, 32);
    a3 += __shfl_xor(a3, 32);
    if (half == 0) {
        const float inv = (end > beg) ? 1.f / denom : 0.f;
        const float4 bv = *(const float4*)&bias[l * 4];
        float4 o = make_float4(a0 * inv + bv.x, a1 * inv + bv.y,
                               a2 * inv + bv.z, a3 * inv + bv.w);
        *(float4*)&out[(unsigned)n * HF + l * 4] = o;
    }
}

// ---------------------------------------------------------------------------
// launch — ws (float units): el 0 / er 200k / cnt 400k / off 450k /
// perm 500k / Wt 1300k / bsum 1316500 (196 u32) / hW 1320k..4520k
// => 18.1 MB (ws-safe).
// 6 dispatches: [zero|prepW] -> [gemm|hist] -> bsum -> scan -> fill -> agg.
// ---------------------------------------------------------------------------
extern "C" void kernel_launch(void* const* d_in, const int* in_sizes, int n_in,
                              void* d_out, int out_size, void* d_ws, size_t ws_size,
                              hipStream_t stream) {
    const float* h    = (const float*)d_in[0];
    const float* W    = (const float*)d_in[1];
    const float* lw   = (const float*)d_in[2];
    const float* lb   = (const float*)d_in[3];
    const float* rw   = (const float*)d_in[4];
    const float* rb   = (const float*)d_in[5];
    const float* bias = (const float*)d_in[6];
    const int*   src  = (const int*)d_in[7];
    const int*   dst  = (const int*)d_in[8];
    float* out = (float*)d_out;

    float*    ws   = (float*)d_ws;
    float*    el   = ws;                           // 200,000 f
    float*    er   = ws + 200000;                  // 200,000 f
    unsigned* cnt  = (unsigned*)(ws + 400000);     //  50,000 u32
    unsigned* off  = (unsigned*)(ws + 450000);     //  50,000 u32
    unsigned* perm = (unsigned*)(ws + 500000);     // 800,000 u32
    __hip_bfloat16* Wt = (__hip_bfloat16*)(ws + 1300000);  // 32,768 bf16
    unsigned* bsum = (unsigned*)(ws + 1316500);    // 196 u32 (gap before hW)
    __hip_bfloat16* hW = (__hip_bfloat16*)(ws + 1320000);  // 6.4M bf16

    k_zero_prep<<<ZERO_BLOCKS + PREP_BLOCKS, 256, 0, stream>>>(cnt, W, Wt);
    k_gemm_hist<<<GEMM_BLOCKS + HIST_FAT_BLOCKS, 256, 0, stream>>>(
        h, Wt, lw, lb, rw, rb, hW, el, er, dst, cnt);
    k_bsum<<<SCAN_BLOCKS, 256, 0, stream>>>(cnt, bsum);
    k_scan<<<SCAN_BLOCKS, 256, 0, stream>>>(cnt, off, bsum);
    k_fill<<<FILL_SLICES * FILL_WINDOWS, 256, 0, stream>>>(src, dst, off, perm);
    k_aggregate<<<N_NODES / 4, 256, 0, stream>>>(hW, el, er, off, perm, bias, out);
}